// Round 2
// baseline (1234.084 us; speedup 1.0000x reference)
//
#include <hip/hip_runtime.h>

// SparseBasicBlock: conv1(gather-GEMM) -> BN+ReLU -> conv2 -> BN -> +residual -> ReLU
// bf16 MFMA (16x16x32), fp32 accum, fp32 BN stats via block reduction + atomics.
// Mask dtype (bool/int32/float32) detected on device; mask folded into eidx with
// a zero-row sentinel at row N.

#define C_CH 128
#define K_OFF 9
#define MTILE 64

typedef __attribute__((ext_vector_type(8))) short bf16x8;
typedef __attribute__((ext_vector_type(4))) float f32x4;
typedef __attribute__((ext_vector_type(8))) unsigned short u16x8;

__device__ __forceinline__ unsigned short f2b(float f) {
    union { float f; unsigned u; } v; v.f = f;
    unsigned r = v.u + 0x7fffu + ((v.u >> 16) & 1u);   // round-to-nearest-even
    return (unsigned short)(r >> 16);
}
__device__ __forceinline__ float b2f(unsigned short h) {
    union { unsigned u; float f; } v; v.u = ((unsigned)h) << 16;
    return v.f;
}

// ---------------- pre-kernels ----------------

// zero stat accumulators + mask-dtype flags + the two zero-sentinel rows
__global__ void init_k(float* stats, unsigned int* zrow1, unsigned int* zrow2) {
    int t = threadIdx.x;
    if (t < 512) stats[t] = 0.f;                 // S1,Q1,S2,Q2
    if (t >= 512 && t < 514) ((int*)stats)[1024 + (t - 512)] = 0;  // flagA, flagB
    if (t < 64) { zrow1[t] = 0u; zrow2[t] = 0u; }
}

// Detect mask encoding from first 16KB of the buffer:
//  int32 0/1  -> bytes at (i&3)!=0 all zero            -> flagA=0
//  uint8 bool -> nonzero bytes at any offset, all <=1  -> flagA=1, flagB=0
//  float32    -> byte values >1 (e.g. 0x3f)            -> flagA=1, flagB=1
__global__ void detect_mask_k(const unsigned char* __restrict__ m, int* flagA, int* flagB) {
    int i = blockIdx.x * blockDim.x + threadIdx.x;   // 16384 threads
    unsigned char v = m[i];
    if ((i & 3) != 0 && v != 0) atomicOr(flagA, 1);
    if (v > 1) atomicOr(flagB, 1);
}

// eidx[i] = mask ? nbr_idx[i] : N   (row N is the zero sentinel)
__global__ void fold_idx_k(const int* __restrict__ nidx, const void* __restrict__ m,
                           const int* __restrict__ flagA, const int* __restrict__ flagB,
                           int* __restrict__ eidx, int n, int N) {
    int i = blockIdx.x * blockDim.x + threadIdx.x;
    if (i >= n) return;
    int fa = *flagA, fb = *flagB;
    bool t;
    if (!fa)       t = ((const int*)m)[i] != 0;        // int32
    else if (fb)   t = ((const unsigned*)m)[i] != 0;   // float32 (bit test; 0.0 is all-zero)
    else           t = ((const unsigned char*)m)[i] != 0;  // uint8 bool
    eidx[i] = t ? nidx[i] : N;
}

__global__ void convert_feat_k(const float* __restrict__ x, unsigned short* __restrict__ y, int n4) {
    int i = blockIdx.x * blockDim.x + threadIdx.x;
    int s = gridDim.x * blockDim.x;
    for (; i < n4; i += s) {
        float4 f = ((const float4*)x)[i];
        ushort4 o;
        o.x = f2b(f.x); o.y = f2b(f.y); o.z = f2b(f.z); o.w = f2b(f.w);
        ((ushort4*)y)[i] = o;
    }
}

// Pack W[9][128][128] fp32 into bf16 MFMA-B fragments:
// Wp[((ko*8+nt)*4+ks)*512 + lane*8 + j] = W[ko][ks*32+(lane>>4)*8+j][nt*16+(lane&15)]
__global__ void pack_w_k(const float* __restrict__ W, unsigned short* __restrict__ Wp) {
    int i = blockIdx.x * blockDim.x + threadIdx.x;
    if (i >= K_OFF * 8 * 4 * 512) return;
    int j = i & 7;
    int l = (i >> 3) & 63;
    int frag = i >> 9;
    int ks = frag & 3;
    int nt = (frag >> 2) & 7;
    int ko = frag >> 5;
    int cin = ks * 32 + (l >> 4) * 8 + j;
    int cout = nt * 16 + (l & 15);
    Wp[i] = f2b(W[ko * C_CH * C_CH + cin * C_CH + cout]);
}

// ---------------- gather-GEMM conv ----------------

__global__ __launch_bounds__(256) void conv_kernel(
    const unsigned short* __restrict__ Xb,   // (N+1) x 128 bf16 (row N = zeros)
    const unsigned short* __restrict__ Wp,   // packed weights (fragment layout)
    const int* __restrict__ eidx,            // N x 9, masked entries -> N
    unsigned short* __restrict__ Yraw,       // N x 128 bf16 raw conv output
    float* __restrict__ statS, float* __restrict__ statQ)
{
    const int tid = threadIdx.x;
    const int lane = tid & 63;
    const int wv = tid >> 6;          // wave 0..3, owns rows [wv*16, wv*16+16)
    const int tile = blockIdx.x * MTILE;

    __shared__ alignas(16) unsigned short At[MTILE * C_CH]; // 16KB, XOR-swizzled
    __shared__ int sIdx[MTILE][K_OFF];
    __shared__ float redS[4][C_CH];
    __shared__ float redQ[4][C_CH];

    if (tid < MTILE) {
        #pragma unroll
        for (int k = 0; k < K_OFF; ++k)
            sIdx[tid][k] = eidx[(tile + tid) * K_OFF + k];
    }

    f32x4 acc[8];
    #pragma unroll
    for (int i = 0; i < 8; ++i) acc[i] = (f32x4){0.f, 0.f, 0.f, 0.f};

    const int r_st = tid >> 4;     // staging row-in-group 0..15
    const int ch_st = tid & 15;    // staging 16B chunk 0..15
    const int arow = wv * 16 + (lane & 15);  // A-fragment row within tile
    const int asub = lane >> 4;              // k-subgroup 0..3

    for (int ko = 0; ko < K_OFF; ++ko) {
        __syncthreads();  // previous iter's LDS reads done (also covers sIdx init)
        // ---- stage gathered A-tile (64 rows x 128 bf16), swizzled ----
        #pragma unroll
        for (int jr = 0; jr < 4; ++jr) {
            int r = jr * 16 + r_st;                 // row in tile 0..63
            int gidx = sIdx[r][ko];
            uint4 v = *(const uint4*)(Xb + (size_t)gidx * C_CH + ch_st * 8);
            int sc = ch_st ^ (r & 7);
            *(uint4*)((char*)At + r * 256 + sc * 16) = v;
        }
        __syncthreads();
        // ---- A fragments from LDS ----
        bf16x8 a[4];
        #pragma unroll
        for (int ks = 0; ks < 4; ++ks) {
            int sc = (ks * 4 + asub) ^ (arow & 7);
            a[ks] = *(const bf16x8*)((const char*)At + arow * 256 + sc * 16);
        }
        // ---- MFMA: 8 n-tiles x 4 k-steps ----
        const unsigned short* wb = Wp + ko * (8 * 4 * 512) + lane * 8;
        #pragma unroll
        for (int nt = 0; nt < 8; ++nt) {
            #pragma unroll
            for (int ks = 0; ks < 4; ++ks) {
                bf16x8 b = *(const bf16x8*)(wb + (nt * 4 + ks) * 512);
                acc[nt] = __builtin_amdgcn_mfma_f32_16x16x32_bf16(a[ks], b, acc[nt], 0, 0, 0);
            }
        }
    }

    // ---- per-channel stats: sum and sumsq over this block's 64 rows ----
    #pragma unroll
    for (int nt = 0; nt < 8; ++nt) {
        float s = acc[nt][0] + acc[nt][1] + acc[nt][2] + acc[nt][3];
        float q = acc[nt][0] * acc[nt][0] + acc[nt][1] * acc[nt][1]
                + acc[nt][2] * acc[nt][2] + acc[nt][3] * acc[nt][3];
        s += __shfl_xor(s, 16); s += __shfl_xor(s, 32);
        q += __shfl_xor(q, 16); q += __shfl_xor(q, 32);
        if (lane < 16) { redS[wv][nt * 16 + lane] = s; redQ[wv][nt * 16 + lane] = q; }
    }

    // ---- write raw conv output (bf16) ----
    #pragma unroll
    for (int nt = 0; nt < 8; ++nt) {
        int col = nt * 16 + (lane & 15);
        #pragma unroll
        for (int r = 0; r < 4; ++r) {
            int row = tile + wv * 16 + asub * 4 + r;
            Yraw[row * C_CH + col] = f2b(acc[nt][r]);
        }
    }

    __syncthreads();
    if (tid < C_CH) {
        float s = redS[0][tid] + redS[1][tid] + redS[2][tid] + redS[3][tid];
        atomicAdd(&statS[tid], s);
    } else if (tid < 2 * C_CH) {
        int c = tid - C_CH;
        float q = redQ[0][c] + redQ[1][c] + redQ[2][c] + redQ[3][c];
        atomicAdd(&statQ[c], q);
    }
}

// ---------------- BN finalize / apply ----------------

__global__ void finalize_bn_k(const float* __restrict__ S, const float* __restrict__ Q,
                              const float* __restrict__ gamma, const float* __restrict__ beta,
                              float* __restrict__ scale, float* __restrict__ bias, float invN) {
    int c = threadIdx.x;
    if (c < C_CH) {
        float mu = S[c] * invN;
        float var = Q[c] * invN - mu * mu;
        float inv = rsqrtf(var + 1e-4f);
        float sc = gamma[c] * inv;
        scale[c] = sc;
        bias[c] = beta[c] - mu * sc;
    }
}

__global__ void bn_relu_k(unsigned short* __restrict__ y,
                          const float* __restrict__ scale, const float* __restrict__ bias, int n8) {
    int i0 = blockIdx.x * blockDim.x + threadIdx.x;
    int S = gridDim.x * blockDim.x;          // S*8 % 128 == 0 -> c0 invariant
    int c0 = (i0 * 8) & (C_CH - 1);
    float sc[8], bs[8];
    #pragma unroll
    for (int j = 0; j < 8; ++j) { sc[j] = scale[c0 + j]; bs[j] = bias[c0 + j]; }
    for (int i = i0; i < n8; i += S) {
        u16x8 v = ((const u16x8*)y)[i];
        #pragma unroll
        for (int j = 0; j < 8; ++j) {
            float x = b2f((unsigned short)v[j]);
            x = fmaxf(x * sc[j] + bs[j], 0.f);
            v[j] = (short)f2b(x);
        }
        ((u16x8*)y)[i] = v;
    }
}

__global__ void final_fuse_k(const unsigned short* __restrict__ raw,
                             const float* __restrict__ feat,
                             const float* __restrict__ scale, const float* __restrict__ bias,
                             float* __restrict__ out, int n4) {
    int i0 = blockIdx.x * blockDim.x + threadIdx.x;
    int S = gridDim.x * blockDim.x;          // S*4 % 128 == 0 -> c0 invariant
    int c0 = (i0 * 4) & (C_CH - 1);
    float sc[4], bs[4];
    #pragma unroll
    for (int j = 0; j < 4; ++j) { sc[j] = scale[c0 + j]; bs[j] = bias[c0 + j]; }
    for (int i = i0; i < n4; i += S) {
        ushort4 r = ((const ushort4*)raw)[i];
        float4 f = ((const float4*)feat)[i];
        float4 o;
        o.x = fmaxf(b2f(r.x) * sc[0] + bs[0] + f.x, 0.f);
        o.y = fmaxf(b2f(r.y) * sc[1] + bs[1] + f.y, 0.f);
        o.z = fmaxf(b2f(r.z) * sc[2] + bs[2] + f.z, 0.f);
        o.w = fmaxf(b2f(r.w) * sc[3] + bs[3] + f.w, 0.f);
        ((float4*)out)[i] = o;
    }
}

// ---------------- launch ----------------

extern "C" void kernel_launch(void* const* d_in, const int* in_sizes, int n_in,
                              void* d_out, int out_size, void* d_ws, size_t ws_size,
                              hipStream_t stream) {
    const float* feat = (const float*)d_in[0];
    const float* W1 = (const float*)d_in[1];
    const float* W2 = (const float*)d_in[2];
    const float* g1 = (const float*)d_in[3];
    const float* b1 = (const float*)d_in[4];
    const float* g2 = (const float*)d_in[5];
    const float* b2 = (const float*)d_in[6];
    const int* nidx = (const int*)d_in[7];
    const void* nmask = d_in[8];

    const int N = in_sizes[0] / C_CH;   // 400000
    const int NK = N * K_OFF;

    char* ws = (char*)d_ws;
    unsigned short* featb = (unsigned short*)ws;                          // (N+1) x 128 bf16
    size_t off = (size_t)(N + 1) * C_CH * 2;
    off = (off + 255) & ~(size_t)255;
    unsigned short* Wp1 = (unsigned short*)(ws + off); off += (size_t)K_OFF * C_CH * C_CH * 2;
    unsigned short* Wp2 = (unsigned short*)(ws + off); off += (size_t)K_OFF * C_CH * C_CH * 2;
    float* stats = (float*)(ws + off);
    float* S1 = stats;        float* Q1 = stats + 128;
    float* S2 = stats + 256;  float* Q2 = stats + 384;
    float* sc1 = stats + 512; float* bi1 = stats + 640;
    float* sc2 = stats + 768; float* bi2 = stats + 896;
    int* flagA = ((int*)stats) + 1024;
    int* flagB = ((int*)stats) + 1025;

    // scratch inside d_out: y1 = rows [0, N] bf16 (~102.4MB); eidx at +128MiB (14.4MB).
    // All of d_out is rewritten by final_fuse_k at the end.
    unsigned short* y1 = (unsigned short*)d_out;
    int* eidx = (int*)((char*)d_out + (size_t)134217728);
    unsigned short* out2raw = featb;               // reuse feat-bf16 region after conv1

    hipLaunchKernelGGL(init_k, dim3(1), dim3(514), 0, stream,
                       stats, (unsigned int*)(featb + (size_t)N * C_CH),
                       (unsigned int*)(y1 + (size_t)N * C_CH));
    hipLaunchKernelGGL(detect_mask_k, dim3(64), dim3(256), 0, stream,
                       (const unsigned char*)nmask, flagA, flagB);
    hipLaunchKernelGGL(convert_feat_k, dim3(2048), dim3(256), 0, stream, feat, featb, N * C_CH / 4);
    hipLaunchKernelGGL(pack_w_k, dim3(576), dim3(256), 0, stream, W1, Wp1);
    hipLaunchKernelGGL(pack_w_k, dim3(576), dim3(256), 0, stream, W2, Wp2);
    hipLaunchKernelGGL(fold_idx_k, dim3((NK + 255) / 256), dim3(256), 0, stream,
                       nidx, nmask, flagA, flagB, eidx, NK, N);

    hipLaunchKernelGGL(conv_kernel, dim3(N / MTILE), dim3(256), 0, stream,
                       featb, Wp1, eidx, y1, S1, Q1);
    hipLaunchKernelGGL(finalize_bn_k, dim3(1), dim3(128), 0, stream, S1, Q1, g1, b1, sc1, bi1, 1.0f / N);
    hipLaunchKernelGGL(bn_relu_k, dim3(2048), dim3(256), 0, stream, y1, sc1, bi1, N * C_CH / 8);

    hipLaunchKernelGGL(conv_kernel, dim3(N / MTILE), dim3(256), 0, stream,
                       y1, Wp2, eidx, out2raw, S2, Q2);
    hipLaunchKernelGGL(finalize_bn_k, dim3(1), dim3(128), 0, stream, S2, Q2, g2, b2, sc2, bi2, 1.0f / N);
    hipLaunchKernelGGL(final_fuse_k, dim3(2048), dim3(256), 0, stream,
                       out2raw, feat, sc2, bi2, (float*)d_out, N * C_CH / 4);
}

// Round 3
// 590.072 us; speedup vs baseline: 2.0914x; 2.0914x over previous
//
#include <hip/hip_runtime.h>

// SparseBasicBlock: conv1(gather-GEMM) -> BN+ReLU -> conv2 -> BN -> +residual -> ReLU
// bf16 MFMA 16x16x32, fp32 accum. Conv: double-buffered gather staging via
// global_load_lds (pre-swizzled source, linear LDS dest), B-fragments in regs
// (wave-split over output cols), one barrier per ko step.

#define C_CH 128
#define K_OFF 9
#define MTILE 64

typedef __attribute__((ext_vector_type(8))) short bf16x8;
typedef __attribute__((ext_vector_type(4))) float f32x4;
typedef __attribute__((ext_vector_type(8))) unsigned short u16x8;

typedef __attribute__((address_space(1))) const unsigned int* gas_p;
typedef __attribute__((address_space(3))) unsigned int* las_p;

__device__ __forceinline__ void gload_lds16(const unsigned short* g, unsigned short* l) {
    __builtin_amdgcn_global_load_lds((gas_p)g, (las_p)l, 16, 0, 0);
}

__device__ __forceinline__ unsigned short f2b(float f) {
    union { float f; unsigned u; } v; v.f = f;
    unsigned r = v.u + 0x7fffu + ((v.u >> 16) & 1u);   // round-to-nearest-even
    return (unsigned short)(r >> 16);
}
__device__ __forceinline__ float b2f(unsigned short h) {
    union { unsigned u; float f; } v; v.u = ((unsigned)h) << 16;
    return v.f;
}

// ---------------- pre-kernels ----------------

// zero stat accumulators + mask-dtype flags + the two zero-sentinel rows
__global__ void init_k(float* stats, unsigned int* zrow1, unsigned int* zrow2) {
    int t = threadIdx.x;
    if (t < 512) stats[t] = 0.f;                 // S1,Q1,S2,Q2
    if (t >= 512 && t < 514) ((int*)stats)[1024 + (t - 512)] = 0;  // flagA, flagB
    if (t < 64) { zrow1[t] = 0u; zrow2[t] = 0u; }
}

// Detect mask encoding from first 16KB (int32 / uint8-bool / float32)
__global__ void detect_mask_k(const unsigned char* __restrict__ m, int* flagA, int* flagB) {
    int i = blockIdx.x * blockDim.x + threadIdx.x;   // 16384 threads
    unsigned char v = m[i];
    if ((i & 3) != 0 && v != 0) atomicOr(flagA, 1);
    if (v > 1) atomicOr(flagB, 1);
}

// eidx[i] = mask ? nbr_idx[i] : N   (row N is the zero sentinel)
__global__ void fold_idx_k(const int* __restrict__ nidx, const void* __restrict__ m,
                           const int* __restrict__ flagA, const int* __restrict__ flagB,
                           int* __restrict__ eidx, int n, int N) {
    int i = blockIdx.x * blockDim.x + threadIdx.x;
    if (i >= n) return;
    int fa = *flagA, fb = *flagB;
    bool t;
    if (!fa)       t = ((const int*)m)[i] != 0;        // int32
    else if (fb)   t = ((const unsigned*)m)[i] != 0;   // float32 bit test
    else           t = ((const unsigned char*)m)[i] != 0;  // uint8 bool
    eidx[i] = t ? nidx[i] : N;
}

__global__ void convert_feat_k(const float* __restrict__ x, unsigned short* __restrict__ y, int n4) {
    int i = blockIdx.x * blockDim.x + threadIdx.x;
    int s = gridDim.x * blockDim.x;
    for (; i < n4; i += s) {
        float4 f = ((const float4*)x)[i];
        ushort4 o;
        o.x = f2b(f.x); o.y = f2b(f.y); o.z = f2b(f.z); o.w = f2b(f.w);
        ((ushort4*)y)[i] = o;
    }
}

// Pack W[9][128][128] fp32 into bf16 MFMA-B fragments:
// Wp[((ko*8+nt)*4+ks)*512 + lane*8 + j] = W[ko][ks*32+(lane>>4)*8+j][nt*16+(lane&15)]
__global__ void pack_w_k(const float* __restrict__ W, unsigned short* __restrict__ Wp) {
    int i = blockIdx.x * blockDim.x + threadIdx.x;
    if (i >= K_OFF * 8 * 4 * 512) return;
    int j = i & 7;
    int l = (i >> 3) & 63;
    int frag = i >> 9;
    int ks = frag & 3;
    int nt = (frag >> 2) & 7;
    int ko = frag >> 5;
    int cin = ks * 32 + (l >> 4) * 8 + j;
    int cout = nt * 16 + (l & 15);
    Wp[i] = f2b(W[ko * C_CH * C_CH + cin * C_CH + cout]);
}

// ---------------- gather-GEMM conv ----------------

__global__ __launch_bounds__(256) void conv_kernel(
    const unsigned short* __restrict__ Xb,   // (N+1) x 128 bf16 (row N = zeros)
    const unsigned short* __restrict__ Wp,   // packed weights (fragment layout)
    const int* __restrict__ eidx,            // N x 9, masked entries -> N
    unsigned short* __restrict__ Yraw,       // N x 128 bf16 raw conv output
    float* __restrict__ statS, float* __restrict__ statQ)
{
    const int tid = threadIdx.x;
    const int lane = tid & 63;
    const int wv = tid >> 6;
    const int tile = blockIdx.x * MTILE;
    const int asub = lane >> 4;              // 0..3
    const int l15 = lane & 15;

    __shared__ alignas(16) unsigned short At[2][MTILE * C_CH]; // 2 x 16KB, linear
    __shared__ int sIdxT[K_OFF][MTILE];

    // stage rulebook indices (transposed for per-ko contiguity)
    for (int i = tid; i < MTILE * K_OFF; i += 256) {
        int r = i / K_OFF, k = i - r * K_OFF;
        sIdxT[k][r] = eidx[(size_t)(tile + r) * K_OFF + k];
    }
    __syncthreads();

    // staging geometry: thread -> rows jr*16 + (tid>>4), 16B chunk (tid&15)
    const int r_st = tid >> 4;      // 0..15
    const int ch_st = tid & 15;     // 0..15

    // STAGE(buf, ko): 4 async global->LDS 16B loads; LDS dest linear
    // (wave-uniform base + lane*16), global source pre-XOR-swizzled so that the
    // swizzled ds_read below recovers the right chunk.
    #define STAGE(buf, ko)                                                        \
        {                                                                         \
            _Pragma("unroll")                                                     \
            for (int jr = 0; jr < 4; ++jr) {                                      \
                int r = jr * 16 + r_st;                                           \
                int g = sIdxT[ko][r];                                             \
                const unsigned short* src =                                       \
                    Xb + (size_t)g * C_CH + ((ch_st ^ (r & 7)) * 8);              \
                unsigned short* dst = &At[buf][r * C_CH + ch_st * 8];             \
                gload_lds16(src, dst);                                            \
            }                                                                     \
        }

    f32x4 acc[4][2];
    #pragma unroll
    for (int m = 0; m < 4; ++m) { acc[m][0] = (f32x4){0,0,0,0}; acc[m][1] = (f32x4){0,0,0,0}; }

    STAGE(0, 0);
    __syncthreads();   // prologue: buf0 ready

    for (int ko = 0; ko < K_OFF; ++ko) {
        const int cur = ko & 1;

        // B fragments for this wave's 2 col-tiles (in regs, reused 4x each)
        bf16x8 bfrag[2][4];
        const unsigned short* wb = Wp + (size_t)ko * (8 * 4 * 512) + lane * 8;
        #pragma unroll
        for (int j = 0; j < 2; ++j)
            #pragma unroll
            for (int ks = 0; ks < 4; ++ks)
                bfrag[j][ks] = *(const bf16x8*)(wb + ((wv * 2 + j) * 4 + ks) * 512);

        // issue next tile's gather (stays in flight through the MFMAs below)
        if (ko < K_OFF - 1) STAGE(cur ^ 1, ko + 1);

        // A fragments from LDS (swizzled read) + MFMA
        #pragma unroll
        for (int m = 0; m < 4; ++m) {
            bf16x8 a[4];
            #pragma unroll
            for (int ks = 0; ks < 4; ++ks) {
                int row = m * 16 + l15;
                int sc = (ks * 4 + asub) ^ (row & 7);
                a[ks] = *(const bf16x8*)((const char*)At[cur] + row * 256 + sc * 16);
            }
            #pragma unroll
            for (int ks = 0; ks < 4; ++ks) {
                acc[m][0] = __builtin_amdgcn_mfma_f32_16x16x32_bf16(a[ks], bfrag[0][ks], acc[m][0], 0, 0, 0);
                acc[m][1] = __builtin_amdgcn_mfma_f32_16x16x32_bf16(a[ks], bfrag[1][ks], acc[m][1], 0, 0, 0);
            }
        }
        __syncthreads();  // drains stage (vmcnt 0) + protects buffer reuse
    }
    #undef STAGE

    // ---- per-channel stats (each wave owns channels [wv*32, wv*32+32)) ----
    #pragma unroll
    for (int j = 0; j < 2; ++j) {
        float s = 0.f, q = 0.f;
        #pragma unroll
        for (int m = 0; m < 4; ++m)
            #pragma unroll
            for (int r = 0; r < 4; ++r) { float v = acc[m][j][r]; s += v; q += v * v; }
        s += __shfl_xor(s, 16); s += __shfl_xor(s, 32);
        q += __shfl_xor(q, 16); q += __shfl_xor(q, 32);
        if (lane < 16) {
            atomicAdd(&statS[wv * 32 + j * 16 + lane], s);
            atomicAdd(&statQ[wv * 32 + j * 16 + lane], q);
        }
    }

    // ---- write raw conv output (bf16) ----
    #pragma unroll
    for (int m = 0; m < 4; ++m)
        #pragma unroll
        for (int j = 0; j < 2; ++j) {
            int col = (wv * 2 + j) * 16 + l15;
            #pragma unroll
            for (int r = 0; r < 4; ++r) {
                int row = tile + m * 16 + asub * 4 + r;
                Yraw[(size_t)row * C_CH + col] = f2b(acc[m][j][r]);
            }
        }
}

// ---------------- BN finalize / apply ----------------

__global__ void finalize_bn_k(const float* __restrict__ S, const float* __restrict__ Q,
                              const float* __restrict__ gamma, const float* __restrict__ beta,
                              float* __restrict__ scale, float* __restrict__ bias, float invN) {
    int c = threadIdx.x;
    if (c < C_CH) {
        float mu = S[c] * invN;
        float var = Q[c] * invN - mu * mu;
        float inv = rsqrtf(var + 1e-4f);
        float sc = gamma[c] * inv;
        scale[c] = sc;
        bias[c] = beta[c] - mu * sc;
    }
}

__global__ void bn_relu_k(unsigned short* __restrict__ y,
                          const float* __restrict__ scale, const float* __restrict__ bias, int n8) {
    int i0 = blockIdx.x * blockDim.x + threadIdx.x;
    int S = gridDim.x * blockDim.x;
    int c0 = (i0 * 8) & (C_CH - 1);
    float sc[8], bs[8];
    #pragma unroll
    for (int j = 0; j < 8; ++j) { sc[j] = scale[c0 + j]; bs[j] = bias[c0 + j]; }
    for (int i = i0; i < n8; i += S) {
        u16x8 v = ((const u16x8*)y)[i];
        #pragma unroll
        for (int j = 0; j < 8; ++j) {
            float x = b2f((unsigned short)v[j]);
            x = fmaxf(x * sc[j] + bs[j], 0.f);
            v[j] = (short)f2b(x);
        }
        ((u16x8*)y)[i] = v;
    }
}

__global__ void final_fuse_k(const unsigned short* __restrict__ raw,
                             const float* __restrict__ feat,
                             const float* __restrict__ scale, const float* __restrict__ bias,
                             float* __restrict__ out, int n4) {
    int i0 = blockIdx.x * blockDim.x + threadIdx.x;
    int S = gridDim.x * blockDim.x;
    int c0 = (i0 * 4) & (C_CH - 1);
    float sc[4], bs[4];
    #pragma unroll
    for (int j = 0; j < 4; ++j) { sc[j] = scale[c0 + j]; bs[j] = bias[c0 + j]; }
    for (int i = i0; i < n4; i += S) {
        ushort4 r = ((const ushort4*)raw)[i];
        float4 f = ((const float4*)feat)[i];
        float4 o;
        o.x = fmaxf(b2f(r.x) * sc[0] + bs[0] + f.x, 0.f);
        o.y = fmaxf(b2f(r.y) * sc[1] + bs[1] + f.y, 0.f);
        o.z = fmaxf(b2f(r.z) * sc[2] + bs[2] + f.z, 0.f);
        o.w = fmaxf(b2f(r.w) * sc[3] + bs[3] + f.w, 0.f);
        ((float4*)out)[i] = o;
    }
}

// ---------------- launch ----------------

extern "C" void kernel_launch(void* const* d_in, const int* in_sizes, int n_in,
                              void* d_out, int out_size, void* d_ws, size_t ws_size,
                              hipStream_t stream) {
    const float* feat = (const float*)d_in[0];
    const float* W1 = (const float*)d_in[1];
    const float* W2 = (const float*)d_in[2];
    const float* g1 = (const float*)d_in[3];
    const float* b1 = (const float*)d_in[4];
    const float* g2 = (const float*)d_in[5];
    const float* b2 = (const float*)d_in[6];
    const int* nidx = (const int*)d_in[7];
    const void* nmask = d_in[8];

    const int N = in_sizes[0] / C_CH;   // 400000
    const int NK = N * K_OFF;

    char* ws = (char*)d_ws;
    unsigned short* featb = (unsigned short*)ws;                          // (N+1) x 128 bf16
    size_t off = (size_t)(N + 1) * C_CH * 2;
    off = (off + 255) & ~(size_t)255;
    unsigned short* Wp1 = (unsigned short*)(ws + off); off += (size_t)K_OFF * C_CH * C_CH * 2;
    unsigned short* Wp2 = (unsigned short*)(ws + off); off += (size_t)K_OFF * C_CH * C_CH * 2;
    float* stats = (float*)(ws + off);
    float* S1 = stats;        float* Q1 = stats + 128;
    float* S2 = stats + 256;  float* Q2 = stats + 384;
    float* sc1 = stats + 512; float* bi1 = stats + 640;
    float* sc2 = stats + 768; float* bi2 = stats + 896;
    int* flagA = ((int*)stats) + 1024;
    int* flagB = ((int*)stats) + 1025;

    // scratch inside d_out: y1 = rows [0, N] bf16 (~102.4MB); eidx at +128MiB.
    unsigned short* y1 = (unsigned short*)d_out;
    int* eidx = (int*)((char*)d_out + (size_t)134217728);
    unsigned short* out2raw = featb;               // reuse feat-bf16 region after conv1

    hipLaunchKernelGGL(init_k, dim3(1), dim3(514), 0, stream,
                       stats, (unsigned int*)(featb + (size_t)N * C_CH),
                       (unsigned int*)(y1 + (size_t)N * C_CH));
    hipLaunchKernelGGL(detect_mask_k, dim3(64), dim3(256), 0, stream,
                       (const unsigned char*)nmask, flagA, flagB);
    hipLaunchKernelGGL(convert_feat_k, dim3(2048), dim3(256), 0, stream, feat, featb, N * C_CH / 4);
    hipLaunchKernelGGL(pack_w_k, dim3(576), dim3(256), 0, stream, W1, Wp1);
    hipLaunchKernelGGL(pack_w_k, dim3(576), dim3(256), 0, stream, W2, Wp2);
    hipLaunchKernelGGL(fold_idx_k, dim3((NK + 255) / 256), dim3(256), 0, stream,
                       nidx, nmask, flagA, flagB, eidx, NK, N);

    hipLaunchKernelGGL(conv_kernel, dim3(N / MTILE), dim3(256), 0, stream,
                       featb, Wp1, eidx, y1, S1, Q1);
    hipLaunchKernelGGL(finalize_bn_k, dim3(1), dim3(128), 0, stream, S1, Q1, g1, b1, sc1, bi1, 1.0f / N);
    hipLaunchKernelGGL(bn_relu_k, dim3(2048), dim3(256), 0, stream, y1, sc1, bi1, N * C_CH / 8);

    hipLaunchKernelGGL(conv_kernel, dim3(N / MTILE), dim3(256), 0, stream,
                       y1, Wp2, eidx, out2raw, S2, Q2);
    hipLaunchKernelGGL(finalize_bn_k, dim3(1), dim3(128), 0, stream, S2, Q2, g2, b2, sc2, bi2, 1.0f / N);
    hipLaunchKernelGGL(final_fuse_k, dim3(2048), dim3(256), 0, stream,
                       out2raw, feat, sc2, bi2, (float*)d_out, N * C_CH / 4);
}

// Round 4
// 574.321 us; speedup vs baseline: 2.1488x; 1.0274x over previous
//
#include <hip/hip_runtime.h>

// SparseBasicBlock: conv1(gather-GEMM) -> BN+ReLU -> conv2 -> BN -> +residual -> ReLU
// bf16 MFMA 16x16x32, fp32 accum. Conv: 3-buffer LDS gather pipeline via
// global_load_lds (pre-swizzled source, linear LDS dest), counted vmcnt +
// raw s_barrier (one barrier per ko), B-fragments in regs (wave-split cols).

#define C_CH 128
#define K_OFF 9
#define MTILE 64

typedef __attribute__((ext_vector_type(8))) short bf16x8;
typedef __attribute__((ext_vector_type(4))) float f32x4;
typedef __attribute__((ext_vector_type(8))) unsigned short u16x8;

typedef __attribute__((address_space(1))) const unsigned int* gas_p;
typedef __attribute__((address_space(3))) unsigned int* las_p;

__device__ __forceinline__ void gload_lds16(const unsigned short* g, unsigned short* l) {
    __builtin_amdgcn_global_load_lds((gas_p)g, (las_p)l, 16, 0, 0);
}

__device__ __forceinline__ unsigned short f2b(float f) {
    union { float f; unsigned u; } v; v.f = f;
    unsigned r = v.u + 0x7fffu + ((v.u >> 16) & 1u);   // round-to-nearest-even
    return (unsigned short)(r >> 16);
}
__device__ __forceinline__ float b2f(unsigned short h) {
    union { unsigned u; float f; } v; v.u = ((unsigned)h) << 16;
    return v.f;
}

// ---------------- pre-kernels ----------------

__global__ void init_k(float* stats, unsigned int* zrow1, unsigned int* zrow2) {
    int t = threadIdx.x;
    if (t < 512) stats[t] = 0.f;                 // S1,Q1,S2,Q2
    if (t >= 512 && t < 514) ((int*)stats)[1024 + (t - 512)] = 0;  // flagA, flagB
    if (t < 64) { zrow1[t] = 0u; zrow2[t] = 0u; }
}

// Detect mask encoding from first 16KB (int32 / uint8-bool / float32)
__global__ void detect_mask_k(const unsigned char* __restrict__ m, int* flagA, int* flagB) {
    int i = blockIdx.x * blockDim.x + threadIdx.x;   // 16384 threads
    unsigned char v = m[i];
    if ((i & 3) != 0 && v != 0) atomicOr(flagA, 1);
    if (v > 1) atomicOr(flagB, 1);
}

// eidx[i] = mask ? nbr_idx[i] : N   (row N is the zero sentinel)
__global__ void fold_idx_k(const int* __restrict__ nidx, const void* __restrict__ m,
                           const int* __restrict__ flagA, const int* __restrict__ flagB,
                           int* __restrict__ eidx, int n, int N) {
    int i = blockIdx.x * blockDim.x + threadIdx.x;
    if (i >= n) return;
    int fa = *flagA, fb = *flagB;
    bool t;
    if (!fa)       t = ((const int*)m)[i] != 0;        // int32
    else if (fb)   t = ((const unsigned*)m)[i] != 0;   // float32 bit test
    else           t = ((const unsigned char*)m)[i] != 0;  // uint8 bool
    eidx[i] = t ? nidx[i] : N;
}

__global__ void convert_feat_k(const float* __restrict__ x, unsigned short* __restrict__ y, int n4) {
    int i = blockIdx.x * blockDim.x + threadIdx.x;
    int s = gridDim.x * blockDim.x;
    for (; i < n4; i += s) {
        float4 f = ((const float4*)x)[i];
        ushort4 o;
        o.x = f2b(f.x); o.y = f2b(f.y); o.z = f2b(f.z); o.w = f2b(f.w);
        ((ushort4*)y)[i] = o;
    }
}

// Pack W[9][128][128] fp32 into bf16 MFMA-B fragments (both weight tensors):
// Wp[((ko*8+nt)*4+ks)*512 + lane*8 + j] = W[ko][ks*32+(lane>>4)*8+j][nt*16+(lane&15)]
__global__ void pack_w_k(const float* __restrict__ W1, unsigned short* __restrict__ Wp1,
                         const float* __restrict__ W2, unsigned short* __restrict__ Wp2) {
    int i = blockIdx.x * blockDim.x + threadIdx.x;
    const int tot = K_OFF * 8 * 4 * 512;
    const float* W = (i < tot) ? W1 : W2;
    unsigned short* Wp = (i < tot) ? Wp1 : Wp2;
    int ii = (i < tot) ? i : i - tot;
    if (i >= 2 * tot) return;
    int j = ii & 7;
    int l = (ii >> 3) & 63;
    int frag = ii >> 9;
    int ks = frag & 3;
    int nt = (frag >> 2) & 7;
    int ko = frag >> 5;
    int cin = ks * 32 + (l >> 4) * 8 + j;
    int cout = nt * 16 + (l & 15);
    Wp[ii] = f2b(W[ko * C_CH * C_CH + cin * C_CH + cout]);
}

// ---------------- gather-GEMM conv ----------------

__global__ __launch_bounds__(256) void conv_kernel(
    const unsigned short* __restrict__ Xb,   // (N+1) x 128 bf16 (row N = zeros)
    const unsigned short* __restrict__ Wp,   // packed weights (fragment layout)
    const int* __restrict__ eidx,            // N x 9, masked entries -> N
    unsigned short* __restrict__ Yraw,       // N x 128 bf16 raw conv output
    float* __restrict__ statS, float* __restrict__ statQ)
{
    const int tid = threadIdx.x;
    const int lane = tid & 63;
    const int wv = tid >> 6;
    const int tile = blockIdx.x * MTILE;
    const int asub = lane >> 4;              // 0..3
    const int l15 = lane & 15;

    __shared__ alignas(16) unsigned short At[3][MTILE * C_CH]; // 3 x 16KB, linear
    __shared__ int sIdxT[K_OFF][MTILE];

    for (int i = tid; i < MTILE * K_OFF; i += 256) {
        int r = i / K_OFF, k = i - r * K_OFF;
        sIdxT[k][r] = eidx[(size_t)(tile + r) * K_OFF + k];
    }
    __syncthreads();

    const int r_st = tid >> 4;      // 0..15
    const int ch_st = tid & 15;     // 0..15

    // STAGE(buf, ko): 4 async global->LDS 16B loads; LDS dest linear
    // (wave-uniform base + lane*16); global source pre-XOR-swizzled so the
    // swizzled ds_read below recovers the right chunk.
    #define STAGE(buf, ko)                                                        \
        {                                                                         \
            _Pragma("unroll")                                                     \
            for (int jr = 0; jr < 4; ++jr) {                                      \
                int r = jr * 16 + r_st;                                           \
                int g = sIdxT[ko][r];                                             \
                const unsigned short* src =                                       \
                    Xb + (size_t)g * C_CH + ((ch_st ^ (r & 7)) * 8);              \
                unsigned short* dst = &At[buf][r * C_CH + ch_st * 8];             \
                gload_lds16(src, dst);                                            \
            }                                                                     \
        }

    f32x4 acc[4][2];
    #pragma unroll
    for (int m = 0; m < 4; ++m) { acc[m][0] = (f32x4){0,0,0,0}; acc[m][1] = (f32x4){0,0,0,0}; }

    // prologue: stage ko=0 and ko=1 (2-deep)
    STAGE(0, 0);
    STAGE(1, 1);

    // Per iteration KO (fully unrolled; vmcnt counts are exact):
    //   [B(KO) loads] [sched_barrier] [s_waitcnt vmcnt(VM)] [s_barrier]
    //   [sched_barrier] [STAGE(KO+2)] [ds_read A + 32 MFMA]
    // VM leaves newer-than-stage(KO) ops outstanding:
    //   iter0: s1(4)+B0(8)=12; iters1-7: B(k-1)8+s(k+1)4+B(k)8=20; iter8: B7+B8=16.
    #define CONV_ITER(KO, VM)                                                     \
        {                                                                         \
            bf16x8 bfrag0[4], bfrag1[4];                                          \
            const unsigned short* wb = Wp + (size_t)(KO) * (8 * 4 * 512) + lane * 8; \
            _Pragma("unroll")                                                     \
            for (int ks = 0; ks < 4; ++ks) {                                      \
                bfrag0[ks] = *(const bf16x8*)(wb + ((wv * 2 + 0) * 4 + ks) * 512);\
                bfrag1[ks] = *(const bf16x8*)(wb + ((wv * 2 + 1) * 4 + ks) * 512);\
            }                                                                     \
            __builtin_amdgcn_sched_barrier(0);                                    \
            asm volatile("s_waitcnt vmcnt(" #VM ")" ::: "memory");                \
            __builtin_amdgcn_s_barrier();                                         \
            __builtin_amdgcn_sched_barrier(0);                                    \
            if ((KO) + 2 < K_OFF) { STAGE((((KO) + 2) % 3), (KO) + 2); }          \
            _Pragma("unroll")                                                     \
            for (int m = 0; m < 4; ++m) {                                         \
                bf16x8 a[4];                                                      \
                _Pragma("unroll")                                                 \
                for (int ks = 0; ks < 4; ++ks) {                                  \
                    int row = m * 16 + l15;                                       \
                    int sc = (ks * 4 + asub) ^ (row & 7);                         \
                    a[ks] = *(const bf16x8*)((const char*)At[(KO) % 3] + row * 256 + sc * 16); \
                }                                                                 \
                _Pragma("unroll")                                                 \
                for (int ks = 0; ks < 4; ++ks) {                                  \
                    acc[m][0] = __builtin_amdgcn_mfma_f32_16x16x32_bf16(a[ks], bfrag0[ks], acc[m][0], 0, 0, 0); \
                    acc[m][1] = __builtin_amdgcn_mfma_f32_16x16x32_bf16(a[ks], bfrag1[ks], acc[m][1], 0, 0, 0); \
                }                                                                 \
            }                                                                     \
        }

    CONV_ITER(0, 12)
    CONV_ITER(1, 20)
    CONV_ITER(2, 20)
    CONV_ITER(3, 20)
    CONV_ITER(4, 20)
    CONV_ITER(5, 20)
    CONV_ITER(6, 20)
    CONV_ITER(7, 20)
    CONV_ITER(8, 16)
    #undef CONV_ITER
    #undef STAGE

    // ---- per-channel stats (each wave owns channels [wv*32, wv*32+32)) ----
    #pragma unroll
    for (int j = 0; j < 2; ++j) {
        float s = 0.f, q = 0.f;
        #pragma unroll
        for (int m = 0; m < 4; ++m)
            #pragma unroll
            for (int r = 0; r < 4; ++r) { float v = acc[m][j][r]; s += v; q += v * v; }
        s += __shfl_xor(s, 16); s += __shfl_xor(s, 32);
        q += __shfl_xor(q, 16); q += __shfl_xor(q, 32);
        if (lane < 16) {
            atomicAdd(&statS[wv * 32 + j * 16 + lane], s);
            atomicAdd(&statQ[wv * 32 + j * 16 + lane], q);
        }
    }

    // ---- write raw conv output (bf16) ----
    #pragma unroll
    for (int m = 0; m < 4; ++m)
        #pragma unroll
        for (int j = 0; j < 2; ++j) {
            int col = (wv * 2 + j) * 16 + l15;
            #pragma unroll
            for (int r = 0; r < 4; ++r) {
                int row = tile + m * 16 + asub * 4 + r;
                Yraw[(size_t)row * C_CH + col] = f2b(acc[m][j][r]);
            }
        }
}

// ---------------- BN finalize / apply ----------------

__global__ void finalize_bn_k(const float* __restrict__ S, const float* __restrict__ Q,
                              const float* __restrict__ gamma, const float* __restrict__ beta,
                              float* __restrict__ scale, float* __restrict__ bias, float invN) {
    int c = threadIdx.x;
    if (c < C_CH) {
        float mu = S[c] * invN;
        float var = Q[c] * invN - mu * mu;
        float inv = rsqrtf(var + 1e-4f);
        float sc = gamma[c] * inv;
        scale[c] = sc;
        bias[c] = beta[c] - mu * sc;
    }
}

__global__ void bn_relu_k(unsigned short* __restrict__ y,
                          const float* __restrict__ scale, const float* __restrict__ bias, int n8) {
    int i0 = blockIdx.x * blockDim.x + threadIdx.x;
    int S = gridDim.x * blockDim.x;
    int c0 = (i0 * 8) & (C_CH - 1);
    float sc[8], bs[8];
    #pragma unroll
    for (int j = 0; j < 8; ++j) { sc[j] = scale[c0 + j]; bs[j] = bias[c0 + j]; }
    for (int i = i0; i < n8; i += S) {
        u16x8 v = ((const u16x8*)y)[i];
        #pragma unroll
        for (int j = 0; j < 8; ++j) {
            float x = b2f((unsigned short)v[j]);
            x = fmaxf(x * sc[j] + bs[j], 0.f);
            v[j] = (short)f2b(x);
        }
        ((u16x8*)y)[i] = v;
    }
}

__global__ void final_fuse_k(const unsigned short* __restrict__ raw,
                             const float* __restrict__ feat,
                             const float* __restrict__ scale, const float* __restrict__ bias,
                             float* __restrict__ out, int n4) {
    int i0 = blockIdx.x * blockDim.x + threadIdx.x;
    int S = gridDim.x * blockDim.x;
    int c0 = (i0 * 4) & (C_CH - 1);
    float sc[4], bs[4];
    #pragma unroll
    for (int j = 0; j < 4; ++j) { sc[j] = scale[c0 + j]; bs[j] = bias[c0 + j]; }
    for (int i = i0; i < n4; i += S) {
        ushort4 r = ((const ushort4*)raw)[i];
        float4 f = ((const float4*)feat)[i];
        float4 o;
        o.x = fmaxf(b2f(r.x) * sc[0] + bs[0] + f.x, 0.f);
        o.y = fmaxf(b2f(r.y) * sc[1] + bs[1] + f.y, 0.f);
        o.z = fmaxf(b2f(r.z) * sc[2] + bs[2] + f.z, 0.f);
        o.w = fmaxf(b2f(r.w) * sc[3] + bs[3] + f.w, 0.f);
        ((float4*)out)[i] = o;
    }
}

// ---------------- launch ----------------

extern "C" void kernel_launch(void* const* d_in, const int* in_sizes, int n_in,
                              void* d_out, int out_size, void* d_ws, size_t ws_size,
                              hipStream_t stream) {
    const float* feat = (const float*)d_in[0];
    const float* W1 = (const float*)d_in[1];
    const float* W2 = (const float*)d_in[2];
    const float* g1 = (const float*)d_in[3];
    const float* b1 = (const float*)d_in[4];
    const float* g2 = (const float*)d_in[5];
    const float* b2 = (const float*)d_in[6];
    const int* nidx = (const int*)d_in[7];
    const void* nmask = d_in[8];

    const int N = in_sizes[0] / C_CH;   // 400000
    const int NK = N * K_OFF;

    char* ws = (char*)d_ws;
    unsigned short* featb = (unsigned short*)ws;                          // (N+1) x 128 bf16
    size_t off = (size_t)(N + 1) * C_CH * 2;
    off = (off + 255) & ~(size_t)255;
    unsigned short* Wp1 = (unsigned short*)(ws + off); off += (size_t)K_OFF * C_CH * C_CH * 2;
    unsigned short* Wp2 = (unsigned short*)(ws + off); off += (size_t)K_OFF * C_CH * C_CH * 2;
    float* stats = (float*)(ws + off);
    float* S1 = stats;        float* Q1 = stats + 128;
    float* S2 = stats + 256;  float* Q2 = stats + 384;
    float* sc1 = stats + 512; float* bi1 = stats + 640;
    float* sc2 = stats + 768; float* bi2 = stats + 896;
    int* flagA = ((int*)stats) + 1024;
    int* flagB = ((int*)stats) + 1025;

    // scratch inside d_out: y1 = rows [0, N] bf16 (~102.4MB); eidx at +128MiB.
    unsigned short* y1 = (unsigned short*)d_out;
    int* eidx = (int*)((char*)d_out + (size_t)134217728);
    unsigned short* out2raw = featb;               // reuse feat-bf16 region after conv1

    hipLaunchKernelGGL(init_k, dim3(1), dim3(514), 0, stream,
                       stats, (unsigned int*)(featb + (size_t)N * C_CH),
                       (unsigned int*)(y1 + (size_t)N * C_CH));
    hipLaunchKernelGGL(detect_mask_k, dim3(64), dim3(256), 0, stream,
                       (const unsigned char*)nmask, flagA, flagB);
    hipLaunchKernelGGL(convert_feat_k, dim3(2048), dim3(256), 0, stream, feat, featb, N * C_CH / 4);
    hipLaunchKernelGGL(pack_w_k, dim3(1152), dim3(256), 0, stream, W1, Wp1, W2, Wp2);
    hipLaunchKernelGGL(fold_idx_k, dim3((NK + 255) / 256), dim3(256), 0, stream,
                       nidx, nmask, flagA, flagB, eidx, NK, N);

    hipLaunchKernelGGL(conv_kernel, dim3(N / MTILE), dim3(256), 0, stream,
                       featb, Wp1, eidx, y1, S1, Q1);
    hipLaunchKernelGGL(finalize_bn_k, dim3(1), dim3(128), 0, stream, S1, Q1, g1, b1, sc1, bi1, 1.0f / N);
    hipLaunchKernelGGL(bn_relu_k, dim3(2048), dim3(256), 0, stream, y1, sc1, bi1, N * C_CH / 8);

    hipLaunchKernelGGL(conv_kernel, dim3(N / MTILE), dim3(256), 0, stream,
                       y1, Wp2, eidx, out2raw, S2, Q2);
    hipLaunchKernelGGL(finalize_bn_k, dim3(1), dim3(128), 0, stream, S2, Q2, g2, b2, sc2, bi2, 1.0f / N);
    hipLaunchKernelGGL(final_fuse_k, dim3(2048), dim3(256), 0, stream,
                       out2raw, feat, sc2, bi2, (float*)d_out, N * C_CH / 4);
}